// Round 1
// baseline (516.257 us; speedup 1.0000x reference)
//
#include <hip/hip_runtime.h>

#define EPS_ALPHA 1e-5f

// Per-neuron DeepPoly ReLU6 relaxation + scatter into the (already zeroed)
// output buffer. Layout (flat fp32, reference return order):
//   [0,    N)            cl
//   [N,   2N)            cu
//   [2N,  2N+M*M)        A_l row-major, M = N+1
//   [2N+M*M, 2N+2*M*M)   A_u row-major
// A_* is zero except diag[i]=diag_*, row N cols [0,N)=bias_*, [M-1,M-1]=1.
__global__ void relu6_relax_fill(const float* __restrict__ lower,
                                 const float* __restrict__ upper,
                                 float* __restrict__ out, int n) {
    int i = blockIdx.x * blockDim.x + threadIdx.x;
    if (i >= n) return;

    float l = lower[i];
    float u = upper[i];

    // guarded denominators — identical to reference so all divisions are finite
    float den_ul = (u > l)    ? (u - l)    : 1.0f;
    float den_6l = (l < 6.0f) ? (6.0f - l) : 1.0f;
    float u_safe = (u > 0.0f) ? u          : 1.0f;

    bool mA = (u > 0.0f) && (u <= 6.0f) && (l >= 0.0f);  // stable active
    bool mB = (u > 0.0f) && (u <= 6.0f) && (l < 0.0f);   // crosses 0
    bool mC = (u > 6.0f) && (l <= 0.0f);                 // crosses 0 and 6
    bool mD = (u > 6.0f) && (l > 0.0f) && (l <= 6.0f);   // crosses 6
    bool mE = (l > 6.0f);                                // saturated
    // (else: u <= 0, dead neuron — everything stays 0)

    float alpha_B = (u < -l) ? EPS_ALPHA : 1.0f;
    float lam_B   = u / den_ul;
    bool  upperSlopeC = ((u - 6.0f) < (6.0f - l));
    float aU_C = upperSlopeC ? (6.0f / den_6l) : EPS_ALPHA;
    float aL_C = (u < -l) ? EPS_ALPHA : (6.0f / u_safe);
    float aU_D = upperSlopeC ? 1.0f : EPS_ALPHA;
    float aL_D = (6.0f - l) / den_ul;

    // masks are mutually exclusive; non-selected reference terms are exact 0,
    // so nested selects are bit-equivalent to the reference's masked sums.
    float diag_u = mA ? 1.0f    : mB ? lam_B   : mC ? aU_C : mD ? aU_D : 0.0f;
    float diag_l = mA ? 1.0f    : mB ? alpha_B : mC ? aL_C : mD ? aL_D : 0.0f;
    float bias_u = mB ? (-lam_B * l)
                 : mC ? (6.0f * (1.0f - aU_C))
                 : mD ? (6.0f * (1.0f - aU_D))
                 : mE ? 6.0f : 0.0f;
    float bias_l = mD ? (l * (1.0f - aL_D))
                 : mE ? 6.0f : 0.0f;
    float cu = mA ? u : mB ? u
             : mC ? (6.0f + aU_C * (u - 6.0f))
             : mD ? (6.0f + aU_D * (u - 6.0f))
             : mE ? 6.0f : 0.0f;
    float cl = mA ? l
             : mB ? (alpha_B * l)
             : mC ? (aL_C * l)
             : mD ? l
             : mE ? 6.0f : 0.0f;

    const long long M = (long long)n + 1;        // 8193
    float* cl_p = out;
    float* cu_p = out + n;
    float* Al   = out + 2LL * n;
    float* Au   = Al + M * M;

    cl_p[i] = cl;
    cu_p[i] = cu;
    Al[(long long)i * M + i] = diag_l;           // diagonal (stride M+1 scatter)
    Au[(long long)i * M + i] = diag_u;
    Al[(long long)n * M + i] = bias_l;           // last row (coalesced)
    Au[(long long)n * M + i] = bias_u;
    if (i == 0) {
        Al[M * M - 1] = 1.0f;
        Au[M * M - 1] = 1.0f;
    }
}

extern "C" void kernel_launch(void* const* d_in, const int* in_sizes, int n_in,
                              void* d_out, int out_size, void* d_ws, size_t ws_size,
                              hipStream_t stream) {
    const float* lower = (const float*)d_in[0];
    const float* upper = (const float*)d_in[1];
    float* out = (float*)d_out;
    int n = in_sizes[0];  // 8192

    // Zero the whole 537 MB output (harness poisons it with 0xAA every call).
    // hipMemsetAsync is graph-capturable and runs at the blit write ceiling.
    hipMemsetAsync(d_out, 0, (size_t)out_size * sizeof(float), stream);

    // Fill diagonals / bias rows / cl / cu / corner ones.
    relu6_relax_fill<<<(n + 255) / 256, 256, 0, stream>>>(lower, upper, out, n);
}